// Round 12
// baseline (328.193 us; speedup 1.0000x reference)
//
#include <hip/hip_runtime.h>

#define NUM_CODES 1024
#define DIM 32
#define ROWS 131072      // 16384 * 8
#define DECAYF 0.99f
#define EPSF 1e-5f
#define CCOST 0.25f
#define SLAB 33792       // 32768 dw + 1024 counts
#define RGROUPS 8        // reduce stage-1 groups (summed inline in k_final)
#define IBLK (SLAB / 256)  // 132
#define TILES_PER_CHUNK 16
#define DBIAS 256.0f     // distance bias: keeps acc strictly negative

typedef __attribute__((ext_vector_type(8))) short short8v;
typedef __attribute__((ext_vector_type(4))) float f32x4;

__device__ __forceinline__ unsigned short bf16_rne(float f) {
    unsigned u = __float_as_uint(f);
    unsigned r = u + 0x7FFFu + ((u >> 16) & 1u);
    return (unsigned short)(r >> 16);
}

// ---------------- K0: prep — bf16 hi/lo B tables + biased norms + sumf2 zero ----
// slot = tile*64 + lane; B-frag layout: col = lane&15 (code within tile),
// k = (lane>>4)*8 + j. nbias[k] = -0.5||e_k||^2 - DBIAS (acc stays negative).
__global__ __launch_bounds__(256) void k_prep(const float* __restrict__ emb,
                                              unsigned short* __restrict__ bhi,
                                              unsigned short* __restrict__ blo,
                                              float* __restrict__ nbias,
                                              float* __restrict__ sumf2) {
    int s = blockIdx.x * 256 + threadIdx.x;   // 0..4095
    if (s == 0) sumf2[0] = 0.0f;
    if (s < NUM_CODES) {
        const float4* e4 = (const float4*)(emb + s * DIM);
        float sum = 0.0f;
#pragma unroll
        for (int j = 0; j < 8; ++j) {
            float4 e = e4[j];
            sum += e.x * e.x + e.y * e.y + e.z * e.z + e.w * e.w;
        }
        nbias[s] = -0.5f * sum - DBIAS;
    }
    int l = s & 63, t = s >> 6;
    int code = t * 16 + (l & 15);
    int koff = (l >> 4) * 8;
    const float* src = emb + code * DIM + koff;
    float4 f0 = *(const float4*)(src);
    float4 f1 = *(const float4*)(src + 4);
    float fv[8] = {f0.x, f0.y, f0.z, f0.w, f1.x, f1.y, f1.z, f1.w};
    short8v h, lo;
#pragma unroll
    for (int j = 0; j < 8; ++j) {
        unsigned short hb = bf16_rne(fv[j]);
        float hf = __uint_as_float((unsigned)hb << 16);
        h[j]  = (short)hb;
        lo[j] = (short)bf16_rne(fv[j] - hf);
    }
    *(short8v*)(bhi + (size_t)s * 8) = h;
    *(short8v*)(blo + (size_t)s * 8) = lo;
}

// ---------------- K1: MFMA distance + argmin + quantized write (LDS-staged B) ----
// 1024-thread block (16 waves), __launch_bounds__(1024,4): 4 waves/EU declared
// -> 128-VGPR cap, enough for the dual-tile SSA body (R11 spilled at the
// default 64-reg cap). Block stages the ENTIRE bhi/blo table (128 KB) + nbias
// into LDS once; each wave scans its 16-tile chunk against its 64 rows
// (4 A-frags), two tiles at a time with separate SSA accumulators (8
// independent MFMA chains) and hoisted read-only C-init per tile.
// acc = f.e - 0.5||e||^2 - 256 < 0 always => raw-bit u32 min == argmin dist.
// Per-(row,code) FP sequence identical to R7/R9/R10/R11 => absmax unchanged.
// C/D layout (m89-verified): col = lane&15, row = (lane>>4)*4 + reg.
__global__ __launch_bounds__(1024, 4) void k_argmin(const float* __restrict__ flat,
                                                    const unsigned short* __restrict__ bhi_g,
                                                    const unsigned short* __restrict__ blo_g,
                                                    const float* __restrict__ nbias,
                                                    const float* __restrict__ emb,
                                                    int* __restrict__ idx_out,
                                                    float* __restrict__ idxf_out,
                                                    float* __restrict__ qout) {
    __shared__ short8v s_bh[4096];     // 64 KB
    __shared__ short8v s_bl[4096];     // 64 KB
    __shared__ float   s_nb[NUM_CODES];   // 4 KB
    __shared__ unsigned s_win[4][256]; // 4 KB
    __shared__ int     s_kwin[256];    // 1 KB

    const int tid  = threadIdx.x;
    const int lane = tid & 63;
    const int wave = tid >> 6;        // 0..15
    const int c    = wave & 3;        // chunk
    const int wrg  = wave >> 2;       // rowgroup
    const int blockbase = blockIdx.x * 256;
    const int rowbase   = blockbase + wrg * 64;
    const int lr = lane & 15;   // A row / B,C col within frag
    const int lg = lane >> 4;   // k-group

    // ---- stage B tables + nbias into LDS (whole block cooperates) ----
    {
        const short8v* gh = (const short8v*)bhi_g;
        const short8v* gl = (const short8v*)blo_g;
#pragma unroll
        for (int i = 0; i < 4; ++i) {
            s_bh[i * 1024 + tid] = gh[i * 1024 + tid];
            s_bl[i * 1024 + tid] = gl[i * 1024 + tid];
        }
        if (tid < NUM_CODES) s_nb[tid] = nbias[tid];
    }

    // ---- load + hi/lo split A (4 row-frags = 64 rows per wave) ----
    short8v ahi[4], alo[4];
#pragma unroll
    for (int rf = 0; rf < 4; ++rf) {
        const float* src = flat + (size_t)(rowbase + rf * 16 + lr) * DIM + lg * 8;
        float4 f0 = *(const float4*)src;
        float4 f1 = *(const float4*)(src + 4);
        float fv[8] = {f0.x, f0.y, f0.z, f0.w, f1.x, f1.y, f1.z, f1.w};
        short8v h, lo;
#pragma unroll
        for (int j = 0; j < 8; ++j) {
            unsigned short hb = bf16_rne(fv[j]);
            float hf = __uint_as_float((unsigned)hb << 16);
            h[j]  = (short)hb;
            lo[j] = (short)bf16_rne(fv[j] - hf);
        }
        ahi[rf] = h; alo[rf] = lo;
    }

    unsigned best[4][4];
#pragma unroll
    for (int rf = 0; rf < 4; ++rf)
#pragma unroll
        for (int q = 0; q < 4; ++q) best[rf][q] = 0xFFFFFFFFu;

    __syncthreads();   // B tables ready

    const int t0 = c * TILES_PER_CHUNK;
#pragma unroll
    for (int tp = 0; tp < TILES_PER_CHUNK / 2; ++tp) {
        const int ta = t0 + 2 * tp;
        const int tb = ta + 1;
        short8v bha = s_bh[ta * 64 + lane];
        short8v bla = s_bl[ta * 64 + lane];
        short8v bhb = s_bh[tb * 64 + lane];
        short8v blb = s_bl[tb * 64 + lane];
        float nna = s_nb[ta * 16 + lr];
        float nnb = s_nb[tb * 16 + lr];
        const f32x4 ca = {nna, nna, nna, nna};   // read-only C-init, shared by rf
        const f32x4 cb = {nnb, nnb, nnb, nnb};
        const unsigned codea = (unsigned)(ta * 16 + lr);
        const unsigned codeb = (unsigned)(tb * 16 + lr);
#pragma unroll
        for (int rf = 0; rf < 4; ++rf) {
            f32x4 va = __builtin_amdgcn_mfma_f32_16x16x32_bf16(ahi[rf], bha, ca, 0, 0, 0);
            f32x4 vb = __builtin_amdgcn_mfma_f32_16x16x32_bf16(ahi[rf], bhb, cb, 0, 0, 0);
            va = __builtin_amdgcn_mfma_f32_16x16x32_bf16(ahi[rf], bla, va, 0, 0, 0);
            vb = __builtin_amdgcn_mfma_f32_16x16x32_bf16(ahi[rf], blb, vb, 0, 0, 0);
            va = __builtin_amdgcn_mfma_f32_16x16x32_bf16(alo[rf], bha, va, 0, 0, 0);
            vb = __builtin_amdgcn_mfma_f32_16x16x32_bf16(alo[rf], blb, vb, 0, 0, 0);
#pragma unroll
            for (int q = 0; q < 4; ++q) {
                unsigned pa = (__float_as_uint(va[q]) & 0xFFFFFC00u) | codea;
                unsigned pb = (__float_as_uint(vb[q]) & 0xFFFFFC00u) | codeb;
                best[rf][q] = min(best[rf][q], min(pa, pb));
            }
        }
    }

    // u32-min reduce across the 16-lane group; stash per-(chunk,row) winner
#pragma unroll
    for (int rf = 0; rf < 4; ++rf) {
#pragma unroll
        for (int q = 0; q < 4; ++q) {
            unsigned b = best[rf][q];
#pragma unroll
            for (int m = 1; m < 16; m <<= 1)
                b = min(b, (unsigned)__shfl_xor((int)b, m));
            if (lr == q) s_win[c][wrg * 64 + rf * 16 + lg * 4 + q] = b;
        }
    }
    __syncthreads();

    if (tid < 256) {
        unsigned pm = min(min(s_win[0][tid], s_win[1][tid]),
                          min(s_win[2][tid], s_win[3][tid]));
        int k = (int)(pm & 1023u);
        s_kwin[tid] = k;
        idx_out[blockbase + tid]  = k;
        idxf_out[blockbase + tid] = (float)k;
    }
    __syncthreads();

    // quantized write: 8 threads per row, coalesced, 2 passes over 256 rows
#pragma unroll
    for (int h = 0; h < 2; ++h) {
        int i2  = h * 1024 + tid;
        int row = i2 >> 3, seg = i2 & 7;
        int k = s_kwin[row];
        float4 e = *(const float4*)(emb + (size_t)k * DIM + seg * 4);
        *(float4*)(qout + (size_t)(blockbase + row) * DIM + seg * 4) = e;
    }
}

// ---------------- K2: stats — LDS-accumulated counts/dw + sum(f^2) ---------
// 256 blocks (1/CU, 132 KB LDS) x 512 threads (8 waves): one row per thread.
__global__ __launch_bounds__(512) void k_scatter(const float* __restrict__ flat,
                                                 const int* __restrict__ idx,
                                                 float* __restrict__ slabs,
                                                 float* __restrict__ sumf2,
                                                 int rows_per_block) {
    __shared__ float acc[SLAB];   // 132 KB
    __shared__ float red[512];
    const int tid = threadIdx.x;
    for (int i = tid; i < SLAB; i += 512) acc[i] = 0.0f;
    __syncthreads();

    const int row0 = blockIdx.x * rows_per_block;
    float sf = 0.0f;
    for (int rr = 0; rr < rows_per_block; rr += 512) {
        int r = row0 + rr + tid;
        int k = idx[r];
        const float4* f4 = (const float4*)(flat + (size_t)r * DIM);
        int kb = k * DIM;
#pragma unroll
        for (int j4 = 0; j4 < 8; ++j4) {
            float4 f = f4[j4];
            sf += f.x * f.x + f.y * f.y + f.z * f.z + f.w * f.w;
            int j = 4 * j4;
            // swizzled LDS layout: entry (k,j) lives at k*32 + ((j+k)&31)
            atomicAdd(&acc[kb + ((j + 0 + k) & 31)], f.x);
            atomicAdd(&acc[kb + ((j + 1 + k) & 31)], f.y);
            atomicAdd(&acc[kb + ((j + 2 + k) & 31)], f.z);
            atomicAdd(&acc[kb + ((j + 3 + k) & 31)], f.w);
        }
        atomicAdd(&acc[32768 + k], 1.0f);
    }
    __syncthreads();

    // flush LDS -> per-block slab (un-swizzle; coalesced global writes)
    float* slab = slabs + (size_t)blockIdx.x * SLAB;
    for (int i = tid; i < 32768; i += 512) {
        int k = i >> 5, j = i & 31;
        slab[i] = acc[(i & ~31) | ((j + k) & 31)];
    }
    for (int i = tid; i < NUM_CODES; i += 512) slab[32768 + i] = acc[32768 + i];

    red[tid] = sf;
    __syncthreads();
    for (int s = 256; s > 0; s >>= 1) {
        if (tid < s) red[tid] += red[tid + s];
        __syncthreads();
    }
    if (tid == 0) atomicAdd(sumf2, red[0]);
}

// ---------------- K2b: slab reduction to RGROUPS partials ----------------
__global__ __launch_bounds__(256) void k_reduce1(const float* __restrict__ slabs,
                                                 float* __restrict__ partial,
                                                 int pcount) {
    int g  = blockIdx.x / IBLK;
    int ib = blockIdx.x % IBLK;
    int i = ib * 256 + threadIdx.x;
    const float* base = slabs + (size_t)g * pcount * SLAB + i;
    float s = 0.0f;
#pragma unroll 4
    for (int p = 0; p < pcount; ++p) s += base[(size_t)p * SLAB];
    partial[(size_t)g * SLAB + i] = s;
}

// ---------------- K3: finalize (single block, 1024 threads) ----------------
// Sums the RGROUPS partials inline; loss via identity:
// sum||e-f||^2 = sum||f||^2 + sum_k c_k||e_k||^2 - 2 sum e_k . dw_k  (f64 accum)
__global__ __launch_bounds__(1024) void k_final(const float* __restrict__ ema_cs,
                                                const float* __restrict__ ema_w,
                                                const float* __restrict__ emb,
                                                const float* __restrict__ partial,
                                                const float* __restrict__ sumf2,
                                                float* __restrict__ out_loss,
                                                float* __restrict__ out_perp,
                                                float* __restrict__ out_emb,
                                                float* __restrict__ out_cs,
                                                float* __restrict__ out_ema_w) {
    int tid = threadIdx.x;
    __shared__ float s_cs[NUM_CODES];
    __shared__ float s_cnt[NUM_CODES];
    __shared__ float red[1024];
    __shared__ double redd[1024];

    float c = 0.0f;
#pragma unroll
    for (int g = 0; g < RGROUPS; ++g) c += partial[(size_t)g * SLAB + 32768 + tid];
    s_cnt[tid] = c;
    float pre = ema_cs[tid] * DECAYF + (1.0f - DECAYF) * c;

    red[tid] = pre;
    __syncthreads();
    for (int s = 512; s > 0; s >>= 1) {
        if (tid < s) red[tid] += red[tid + s];
        __syncthreads();
    }
    float n = red[0];
    __syncthreads();

    float ncs = (pre + EPSF) / (n + (float)NUM_CODES * EPSF) * n;
    s_cs[tid] = ncs;
    out_cs[tid] = ncs;

    float p = c / (float)ROWS;
    red[tid] = p * logf(p + 1e-10f);
    __syncthreads();
    for (int s = 512; s > 0; s >>= 1) {
        if (tid < s) red[tid] += red[tid + s];
        __syncthreads();
    }
    float nplogp = red[0];
    __syncthreads();

    // dw pass: EMA update, new embedding, and loss terms
    double lterm = 0.0;   // c_k e^2 - 2 e . dw, accumulated elementwise
    for (int i = tid; i < NUM_CODES * DIM; i += 1024) {
        int k = i >> 5;
        float dwv = 0.0f;
#pragma unroll
        for (int g = 0; g < RGROUPS; ++g) dwv += partial[(size_t)g * SLAB + i];
        float e = emb[i];
        lterm += (double)e * ((double)e * (double)s_cnt[k] - 2.0 * (double)dwv);
        float w = ema_w[i] * DECAYF + (1.0f - DECAYF) * dwv;
        out_ema_w[i] = w;
        out_emb[i] = w / s_cs[k];
    }
    redd[tid] = lterm;
    __syncthreads();
    for (int s = 512; s > 0; s >>= 1) {
        if (tid < s) redd[tid] += redd[tid + s];
        __syncthreads();
    }
    if (tid == 0) {
        double lsum = (double)sumf2[0] + redd[0];
        out_loss[0] = (float)(CCOST * lsum / (double)((size_t)ROWS * DIM));
        out_perp[0] = expf(-nplogp);
    }
}

extern "C" void kernel_launch(void* const* d_in, const int* in_sizes, int n_in,
                              void* d_out, int out_size, void* d_ws, size_t ws_size,
                              hipStream_t stream) {
    const float* inputs    = (const float*)d_in[0];   // [16384,256]
    const float* embedding = (const float*)d_in[1];   // [1024,32]
    const float* ema_cs    = (const float*)d_in[2];   // [1024]
    const float* ema_w     = (const float*)d_in[3];   // [1024,32]

    // output layout (flat f32, return order)
    float* out        = (float*)d_out;
    float* out_loss   = out;                       // 1
    float* out_q      = out + 1;                   // 4194304
    float* out_perp   = out + 4194305;             // 1
    float* out_idxf   = out + 4194306;             // 131072
    float* out_emb    = out + 4325378;             // 32768
    float* out_cs     = out + 4358146;             // 1024
    float* out_ema_w  = out + 4359170;             // 32768

    // workspace layout (bytes)
    char* ws = (char*)d_ws;
    float* nbias      = (float*)(ws);                // 1024 f32   @ 0
    float* sumf2      = (float*)(ws + 4096);         // 1 f32      @ 4096
    int*   idx        = (int*)(ws + 8192);           // 131072 i32 @ 8192 .. 532480
    unsigned short* bhi_g = (unsigned short*)(ws + 532480);  // 64 KB .. 598016
    unsigned short* blo_g = (unsigned short*)(ws + 598016);  // 64 KB .. 663552
    float* partial    = (float*)(ws + 663552);       // 8*33792 f32 .. 1744896
    float* slabs      = (float*)(ws + 1744896);      // P * 33792 f32

    size_t slab_off = 1744896;
    size_t avail = (ws_size > slab_off) ? (ws_size - slab_off) : 0;
    int P = 32;   // minimum fallback
    if (avail >= (size_t)256 * SLAB * 4) P = 256;
    else if (avail >= (size_t)128 * SLAB * 4) P = 128;
    else if (avail >= (size_t)64 * SLAB * 4) P = 64;
    int rows_per_block = ROWS / P;

    k_prep   <<<16, 256, 0, stream>>>(embedding, bhi_g, blo_g, nbias, sumf2);
    k_argmin <<<ROWS / 256, 1024, 0, stream>>>(inputs, bhi_g, blo_g, nbias, embedding,
                                               idx, out_idxf, out_q);
    k_scatter<<<P, 512, 0, stream>>>(inputs, idx, slabs, sumf2, rows_per_block);
    k_reduce1<<<RGROUPS * IBLK, 256, 0, stream>>>(slabs, partial, P / RGROUPS);
    k_final  <<<1, 1024, 0, stream>>>(ema_cs, ema_w, embedding, partial, sumf2,
                                      out_loss, out_perp, out_emb, out_cs, out_ema_w);
}

// Round 13
// 314.446 us; speedup vs baseline: 1.0437x; 1.0437x over previous
//
#include <hip/hip_runtime.h>

#define NUM_CODES 1024
#define DIM 32
#define ROWS 131072      // 16384 * 8
#define DECAYF 0.99f
#define EPSF 1e-5f
#define CCOST 0.25f
#define SLAB 33792       // 32768 dw + 1024 counts
#define RGROUPS 8        // reduce stage-1 groups (summed inline in k_final)
#define IBLK (SLAB / 256)  // 132
#define TILES_PER_CHUNK 16
#define DBIAS 256.0f     // distance bias: keeps acc strictly negative

typedef __attribute__((ext_vector_type(8))) short short8v;
typedef __attribute__((ext_vector_type(4))) float f32x4;

__device__ __forceinline__ unsigned short bf16_rne(float f) {
    unsigned u = __float_as_uint(f);
    unsigned r = u + 0x7FFFu + ((u >> 16) & 1u);
    return (unsigned short)(r >> 16);
}

// ---------------- K0: prep — bf16 hi/lo B tables + biased norms + sumf2 zero ----
// slot = tile*64 + lane; B-frag layout: col = lane&15 (code within tile),
// k = (lane>>4)*8 + j. nbias[k] = -0.5||e_k||^2 - DBIAS (acc stays negative).
__global__ __launch_bounds__(256) void k_prep(const float* __restrict__ emb,
                                              unsigned short* __restrict__ bhi,
                                              unsigned short* __restrict__ blo,
                                              float* __restrict__ nbias,
                                              float* __restrict__ sumf2) {
    int s = blockIdx.x * 256 + threadIdx.x;   // 0..4095
    if (s == 0) sumf2[0] = 0.0f;
    if (s < NUM_CODES) {
        const float4* e4 = (const float4*)(emb + s * DIM);
        float sum = 0.0f;
#pragma unroll
        for (int j = 0; j < 8; ++j) {
            float4 e = e4[j];
            sum += e.x * e.x + e.y * e.y + e.z * e.z + e.w * e.w;
        }
        nbias[s] = -0.5f * sum - DBIAS;
    }
    int l = s & 63, t = s >> 6;
    int code = t * 16 + (l & 15);
    int koff = (l >> 4) * 8;
    const float* src = emb + code * DIM + koff;
    float4 f0 = *(const float4*)(src);
    float4 f1 = *(const float4*)(src + 4);
    float fv[8] = {f0.x, f0.y, f0.z, f0.w, f1.x, f1.y, f1.z, f1.w};
    short8v h, lo;
#pragma unroll
    for (int j = 0; j < 8; ++j) {
        unsigned short hb = bf16_rne(fv[j]);
        float hf = __uint_as_float((unsigned)hb << 16);
        h[j]  = (short)hb;
        lo[j] = (short)bf16_rne(fv[j] - hf);
    }
    *(short8v*)(bhi + (size_t)s * 8) = h;
    *(short8v*)(blo + (size_t)s * 8) = lo;
}

// ---------------- K1: MFMA distance + argmin + quantized write (LDS-staged B) ----
// 1024-thread block (16 waves), __launch_bounds__(1024,1): hipcc's 2nd arg is
// min WORKGROUPS/CU (CUDA semantics — R5/R11/R12 all spilled because 4 wg/CU
// clamped the cap to 64 VGPR). 1 wg/CU (LDS forces it anyway) -> 128-VGPR cap,
// enough for the dual-tile SSA body. Block stages the ENTIRE bhi/blo table
// (128 KB) + nbias into LDS once; each wave scans its 16-tile chunk against
// its 64 rows (4 A-frags), two tiles at a time with separate SSA accumulators
// (8 independent MFMA chains) and hoisted read-only C-init per tile.
// acc = f.e - 0.5||e||^2 - 256 < 0 always => raw-bit u32 min == argmin dist.
// Per-(row,code) FP term order identical to R7/R9/R10 => absmax unchanged.
// C/D layout (m89-verified): col = lane&15, row = (lane>>4)*4 + reg.
__global__ __launch_bounds__(1024, 1) void k_argmin(const float* __restrict__ flat,
                                                    const unsigned short* __restrict__ bhi_g,
                                                    const unsigned short* __restrict__ blo_g,
                                                    const float* __restrict__ nbias,
                                                    const float* __restrict__ emb,
                                                    int* __restrict__ idx_out,
                                                    float* __restrict__ idxf_out,
                                                    float* __restrict__ qout) {
    __shared__ short8v s_bh[4096];     // 64 KB
    __shared__ short8v s_bl[4096];     // 64 KB
    __shared__ float   s_nb[NUM_CODES];   // 4 KB
    __shared__ unsigned s_win[4][256]; // 4 KB
    __shared__ int     s_kwin[256];    // 1 KB

    const int tid  = threadIdx.x;
    const int lane = tid & 63;
    const int wave = tid >> 6;        // 0..15
    const int c    = wave & 3;        // chunk
    const int wrg  = wave >> 2;       // rowgroup
    const int blockbase = blockIdx.x * 256;
    const int rowbase   = blockbase + wrg * 64;
    const int lr = lane & 15;   // A row / B,C col within frag
    const int lg = lane >> 4;   // k-group

    // ---- stage B tables + nbias into LDS (whole block cooperates) ----
    {
        const short8v* gh = (const short8v*)bhi_g;
        const short8v* gl = (const short8v*)blo_g;
#pragma unroll
        for (int i = 0; i < 4; ++i) {
            s_bh[i * 1024 + tid] = gh[i * 1024 + tid];
            s_bl[i * 1024 + tid] = gl[i * 1024 + tid];
        }
        if (tid < NUM_CODES) s_nb[tid] = nbias[tid];
    }

    // ---- load + hi/lo split A (4 row-frags = 64 rows per wave) ----
    short8v ahi[4], alo[4];
#pragma unroll
    for (int rf = 0; rf < 4; ++rf) {
        const float* src = flat + (size_t)(rowbase + rf * 16 + lr) * DIM + lg * 8;
        float4 f0 = *(const float4*)src;
        float4 f1 = *(const float4*)(src + 4);
        float fv[8] = {f0.x, f0.y, f0.z, f0.w, f1.x, f1.y, f1.z, f1.w};
        short8v h, lo;
#pragma unroll
        for (int j = 0; j < 8; ++j) {
            unsigned short hb = bf16_rne(fv[j]);
            float hf = __uint_as_float((unsigned)hb << 16);
            h[j]  = (short)hb;
            lo[j] = (short)bf16_rne(fv[j] - hf);
        }
        ahi[rf] = h; alo[rf] = lo;
    }

    unsigned best[4][4];
#pragma unroll
    for (int rf = 0; rf < 4; ++rf)
#pragma unroll
        for (int q = 0; q < 4; ++q) best[rf][q] = 0xFFFFFFFFu;

    __syncthreads();   // B tables ready

    const int t0 = c * TILES_PER_CHUNK;
#pragma unroll
    for (int tp = 0; tp < TILES_PER_CHUNK / 2; ++tp) {
        const int ta = t0 + 2 * tp;
        const int tb = ta + 1;
        short8v bha = s_bh[ta * 64 + lane];
        short8v bla = s_bl[ta * 64 + lane];
        short8v bhb = s_bh[tb * 64 + lane];
        short8v blb = s_bl[tb * 64 + lane];
        float nna = s_nb[ta * 16 + lr];
        float nnb = s_nb[tb * 16 + lr];
        const f32x4 ca = {nna, nna, nna, nna};   // read-only C-init, shared by rf
        const f32x4 cb = {nnb, nnb, nnb, nnb};
        const unsigned codea = (unsigned)(ta * 16 + lr);
        const unsigned codeb = (unsigned)(tb * 16 + lr);
#pragma unroll
        for (int rf = 0; rf < 4; ++rf) {
            f32x4 va = __builtin_amdgcn_mfma_f32_16x16x32_bf16(ahi[rf], bha, ca, 0, 0, 0);
            f32x4 vb = __builtin_amdgcn_mfma_f32_16x16x32_bf16(ahi[rf], bhb, cb, 0, 0, 0);
            va = __builtin_amdgcn_mfma_f32_16x16x32_bf16(ahi[rf], bla, va, 0, 0, 0);
            vb = __builtin_amdgcn_mfma_f32_16x16x32_bf16(ahi[rf], blb, vb, 0, 0, 0);
            va = __builtin_amdgcn_mfma_f32_16x16x32_bf16(alo[rf], bha, va, 0, 0, 0);
            vb = __builtin_amdgcn_mfma_f32_16x16x32_bf16(alo[rf], bhb, vb, 0, 0, 0);
#pragma unroll
            for (int q = 0; q < 4; ++q) {
                unsigned pa = (__float_as_uint(va[q]) & 0xFFFFFC00u) | codea;
                unsigned pb = (__float_as_uint(vb[q]) & 0xFFFFFC00u) | codeb;
                best[rf][q] = min(best[rf][q], min(pa, pb));
            }
        }
    }

    // u32-min reduce across the 16-lane group; stash per-(chunk,row) winner
#pragma unroll
    for (int rf = 0; rf < 4; ++rf) {
#pragma unroll
        for (int q = 0; q < 4; ++q) {
            unsigned b = best[rf][q];
#pragma unroll
            for (int m = 1; m < 16; m <<= 1)
                b = min(b, (unsigned)__shfl_xor((int)b, m));
            if (lr == q) s_win[c][wrg * 64 + rf * 16 + lg * 4 + q] = b;
        }
    }
    __syncthreads();

    if (tid < 256) {
        unsigned pm = min(min(s_win[0][tid], s_win[1][tid]),
                          min(s_win[2][tid], s_win[3][tid]));
        int k = (int)(pm & 1023u);
        s_kwin[tid] = k;
        idx_out[blockbase + tid]  = k;
        idxf_out[blockbase + tid] = (float)k;
    }
    __syncthreads();

    // quantized write: 8 threads per row, coalesced, 2 passes over 256 rows
#pragma unroll
    for (int h = 0; h < 2; ++h) {
        int i2  = h * 1024 + tid;
        int row = i2 >> 3, seg = i2 & 7;
        int k = s_kwin[row];
        float4 e = *(const float4*)(emb + (size_t)k * DIM + seg * 4);
        *(float4*)(qout + (size_t)(blockbase + row) * DIM + seg * 4) = e;
    }
}

// ---------------- K2: stats — LDS-accumulated counts/dw + sum(f^2) ---------
// 256 blocks (1/CU, 132 KB LDS) x 512 threads (8 waves): one row per thread.
__global__ __launch_bounds__(512) void k_scatter(const float* __restrict__ flat,
                                                 const int* __restrict__ idx,
                                                 float* __restrict__ slabs,
                                                 float* __restrict__ sumf2,
                                                 int rows_per_block) {
    __shared__ float acc[SLAB];   // 132 KB
    __shared__ float red[512];
    const int tid = threadIdx.x;
    for (int i = tid; i < SLAB; i += 512) acc[i] = 0.0f;
    __syncthreads();

    const int row0 = blockIdx.x * rows_per_block;
    float sf = 0.0f;
    for (int rr = 0; rr < rows_per_block; rr += 512) {
        int r = row0 + rr + tid;
        int k = idx[r];
        const float4* f4 = (const float4*)(flat + (size_t)r * DIM);
        int kb = k * DIM;
#pragma unroll
        for (int j4 = 0; j4 < 8; ++j4) {
            float4 f = f4[j4];
            sf += f.x * f.x + f.y * f.y + f.z * f.z + f.w * f.w;
            int j = 4 * j4;
            // swizzled LDS layout: entry (k,j) lives at k*32 + ((j+k)&31)
            atomicAdd(&acc[kb + ((j + 0 + k) & 31)], f.x);
            atomicAdd(&acc[kb + ((j + 1 + k) & 31)], f.y);
            atomicAdd(&acc[kb + ((j + 2 + k) & 31)], f.z);
            atomicAdd(&acc[kb + ((j + 3 + k) & 31)], f.w);
        }
        atomicAdd(&acc[32768 + k], 1.0f);
    }
    __syncthreads();

    // flush LDS -> per-block slab (un-swizzle; coalesced global writes)
    float* slab = slabs + (size_t)blockIdx.x * SLAB;
    for (int i = tid; i < 32768; i += 512) {
        int k = i >> 5, j = i & 31;
        slab[i] = acc[(i & ~31) | ((j + k) & 31)];
    }
    for (int i = tid; i < NUM_CODES; i += 512) slab[32768 + i] = acc[32768 + i];

    red[tid] = sf;
    __syncthreads();
    for (int s = 256; s > 0; s >>= 1) {
        if (tid < s) red[tid] += red[tid + s];
        __syncthreads();
    }
    if (tid == 0) atomicAdd(sumf2, red[0]);
}

// ---------------- K2b: slab reduction to RGROUPS partials ----------------
__global__ __launch_bounds__(256) void k_reduce1(const float* __restrict__ slabs,
                                                 float* __restrict__ partial,
                                                 int pcount) {
    int g  = blockIdx.x / IBLK;
    int ib = blockIdx.x % IBLK;
    int i = ib * 256 + threadIdx.x;
    const float* base = slabs + (size_t)g * pcount * SLAB + i;
    float s = 0.0f;
#pragma unroll 4
    for (int p = 0; p < pcount; ++p) s += base[(size_t)p * SLAB];
    partial[(size_t)g * SLAB + i] = s;
}

// ---------------- K3: finalize (single block, 1024 threads) ----------------
// Sums the RGROUPS partials inline; loss via identity:
// sum||e-f||^2 = sum||f||^2 + sum_k c_k||e_k||^2 - 2 sum e_k . dw_k  (f64 accum)
__global__ __launch_bounds__(1024) void k_final(const float* __restrict__ ema_cs,
                                                const float* __restrict__ ema_w,
                                                const float* __restrict__ emb,
                                                const float* __restrict__ partial,
                                                const float* __restrict__ sumf2,
                                                float* __restrict__ out_loss,
                                                float* __restrict__ out_perp,
                                                float* __restrict__ out_emb,
                                                float* __restrict__ out_cs,
                                                float* __restrict__ out_ema_w) {
    int tid = threadIdx.x;
    __shared__ float s_cs[NUM_CODES];
    __shared__ float s_cnt[NUM_CODES];
    __shared__ float red[1024];
    __shared__ double redd[1024];

    float c = 0.0f;
#pragma unroll
    for (int g = 0; g < RGROUPS; ++g) c += partial[(size_t)g * SLAB + 32768 + tid];
    s_cnt[tid] = c;
    float pre = ema_cs[tid] * DECAYF + (1.0f - DECAYF) * c;

    red[tid] = pre;
    __syncthreads();
    for (int s = 512; s > 0; s >>= 1) {
        if (tid < s) red[tid] += red[tid + s];
        __syncthreads();
    }
    float n = red[0];
    __syncthreads();

    float ncs = (pre + EPSF) / (n + (float)NUM_CODES * EPSF) * n;
    s_cs[tid] = ncs;
    out_cs[tid] = ncs;

    float p = c / (float)ROWS;
    red[tid] = p * logf(p + 1e-10f);
    __syncthreads();
    for (int s = 512; s > 0; s >>= 1) {
        if (tid < s) red[tid] += red[tid + s];
        __syncthreads();
    }
    float nplogp = red[0];
    __syncthreads();

    // dw pass: EMA update, new embedding, and loss terms
    double lterm = 0.0;   // c_k e^2 - 2 e . dw, accumulated elementwise
    for (int i = tid; i < NUM_CODES * DIM; i += 1024) {
        int k = i >> 5;
        float dwv = 0.0f;
#pragma unroll
        for (int g = 0; g < RGROUPS; ++g) dwv += partial[(size_t)g * SLAB + i];
        float e = emb[i];
        lterm += (double)e * ((double)e * (double)s_cnt[k] - 2.0 * (double)dwv);
        float w = ema_w[i] * DECAYF + (1.0f - DECAYF) * dwv;
        out_ema_w[i] = w;
        out_emb[i] = w / s_cs[k];
    }
    redd[tid] = lterm;
    __syncthreads();
    for (int s = 512; s > 0; s >>= 1) {
        if (tid < s) redd[tid] += redd[tid + s];
        __syncthreads();
    }
    if (tid == 0) {
        double lsum = (double)sumf2[0] + redd[0];
        out_loss[0] = (float)(CCOST * lsum / (double)((size_t)ROWS * DIM));
        out_perp[0] = expf(-nplogp);
    }
}

extern "C" void kernel_launch(void* const* d_in, const int* in_sizes, int n_in,
                              void* d_out, int out_size, void* d_ws, size_t ws_size,
                              hipStream_t stream) {
    const float* inputs    = (const float*)d_in[0];   // [16384,256]
    const float* embedding = (const float*)d_in[1];   // [1024,32]
    const float* ema_cs    = (const float*)d_in[2];   // [1024]
    const float* ema_w     = (const float*)d_in[3];   // [1024,32]

    // output layout (flat f32, return order)
    float* out        = (float*)d_out;
    float* out_loss   = out;                       // 1
    float* out_q      = out + 1;                   // 4194304
    float* out_perp   = out + 4194305;             // 1
    float* out_idxf   = out + 4194306;             // 131072
    float* out_emb    = out + 4325378;             // 32768
    float* out_cs     = out + 4358146;             // 1024
    float* out_ema_w  = out + 4359170;             // 32768

    // workspace layout (bytes)
    char* ws = (char*)d_ws;
    float* nbias      = (float*)(ws);                // 1024 f32   @ 0
    float* sumf2      = (float*)(ws + 4096);         // 1 f32      @ 4096
    int*   idx        = (int*)(ws + 8192);           // 131072 i32 @ 8192 .. 532480
    unsigned short* bhi_g = (unsigned short*)(ws + 532480);  // 64 KB .. 598016
    unsigned short* blo_g = (unsigned short*)(ws + 598016);  // 64 KB .. 663552
    float* partial    = (float*)(ws + 663552);       // 8*33792 f32 .. 1744896
    float* slabs      = (float*)(ws + 1744896);      // P * 33792 f32

    size_t slab_off = 1744896;
    size_t avail = (ws_size > slab_off) ? (ws_size - slab_off) : 0;
    int P = 32;   // minimum fallback
    if (avail >= (size_t)256 * SLAB * 4) P = 256;
    else if (avail >= (size_t)128 * SLAB * 4) P = 128;
    else if (avail >= (size_t)64 * SLAB * 4) P = 64;
    int rows_per_block = ROWS / P;

    k_prep   <<<16, 256, 0, stream>>>(embedding, bhi_g, blo_g, nbias, sumf2);
    k_argmin <<<ROWS / 256, 1024, 0, stream>>>(inputs, bhi_g, blo_g, nbias, embedding,
                                               idx, out_idxf, out_q);
    k_scatter<<<P, 512, 0, stream>>>(inputs, idx, slabs, sumf2, rows_per_block);
    k_reduce1<<<RGROUPS * IBLK, 256, 0, stream>>>(slabs, partial, P / RGROUPS);
    k_final  <<<1, 1024, 0, stream>>>(ema_cs, ema_w, embedding, partial, sumf2,
                                      out_loss, out_perp, out_emb, out_cs, out_ema_w);
}

// Round 14
// 114.798 us; speedup vs baseline: 2.8589x; 2.7391x over previous
//
#include <hip/hip_runtime.h>

#define NUM_CODES 1024
#define DIM 32
#define ROWS 131072      // 16384 * 8
#define DECAYF 0.99f
#define EPSF 1e-5f
#define CCOST 0.25f
#define SLAB 33792       // 32768 dw + 1024 counts
#define IBLK (SLAB / 256)  // 132
#define TILES_PER_CHUNK 16
#define ROWS_PER_ABLOCK 512
#define DBIAS 256.0f     // distance bias: keeps acc strictly negative

typedef __attribute__((ext_vector_type(8))) short short8v;
typedef __attribute__((ext_vector_type(4))) float f32x4;

__device__ __forceinline__ unsigned short bf16_rne(float f) {
    unsigned u = __float_as_uint(f);
    unsigned r = u + 0x7FFFu + ((u >> 16) & 1u);
    return (unsigned short)(r >> 16);
}

// ---------------- K0: prep — bf16 hi/lo B tables + biased norms + sumf2 zero ----
// slot = tile*64 + lane; B-frag layout: col = lane&15 (code within tile),
// k = (lane>>4)*8 + j. nbias[k] = -0.5||e_k||^2 - DBIAS (acc stays negative).
__global__ __launch_bounds__(256) void k_prep(const float* __restrict__ emb,
                                              unsigned short* __restrict__ bhi,
                                              unsigned short* __restrict__ blo,
                                              float* __restrict__ nbias,
                                              float* __restrict__ sumf2) {
    int s = blockIdx.x * 256 + threadIdx.x;   // 0..4095
    if (s == 0) sumf2[0] = 0.0f;
    if (s < NUM_CODES) {
        const float4* e4 = (const float4*)(emb + s * DIM);
        float sum = 0.0f;
#pragma unroll
        for (int j = 0; j < 8; ++j) {
            float4 e = e4[j];
            sum += e.x * e.x + e.y * e.y + e.z * e.z + e.w * e.w;
        }
        nbias[s] = -0.5f * sum - DBIAS;
    }
    int l = s & 63, t = s >> 6;
    int code = t * 16 + (l & 15);
    int koff = (l >> 4) * 8;
    const float* src = emb + code * DIM + koff;
    float4 f0 = *(const float4*)(src);
    float4 f1 = *(const float4*)(src + 4);
    float fv[8] = {f0.x, f0.y, f0.z, f0.w, f1.x, f1.y, f1.z, f1.w};
    short8v h, lo;
#pragma unroll
    for (int j = 0; j < 8; ++j) {
        unsigned short hb = bf16_rne(fv[j]);
        float hf = __uint_as_float((unsigned)hb << 16);
        h[j]  = (short)hb;
        lo[j] = (short)bf16_rne(fv[j] - hf);
    }
    *(short8v*)(bhi + (size_t)s * 8) = h;
    *(short8v*)(blo + (size_t)s * 8) = lo;
}

// ---------------- K1: MFMA distance + argmin + quantized write (LDS-staged B) ----
// Grid 256 = 1 block/CU. 1024-thread block (16 waves): wave = (rowgroup
// wrg = wave>>2) x (chunk c = wave&3). Block stages the ENTIRE bhi/blo table
// (128 KB) + nbias into LDS once, then each wave makes TWO row-passes (64 rows
// each, 4 A-frags, R10's proven 52-VGPR single-tile body) over its 16-tile
// chunk. Winners (packed u32: truncated acc bits | code) combined in LDS.
// acc = f.e - 0.5||e||^2 - 256 < 0 always => raw-bit u32 min == argmin dist.
// Per-(row,code) FP sequence identical to R10 => absmax unchanged (981).
// C/D layout (m89-verified): col = lane&15, row = (lane>>4)*4 + reg.
__global__ __launch_bounds__(1024) void k_argmin(const float* __restrict__ flat,
                                                 const unsigned short* __restrict__ bhi_g,
                                                 const unsigned short* __restrict__ blo_g,
                                                 const float* __restrict__ nbias,
                                                 const float* __restrict__ emb,
                                                 int* __restrict__ idx_out,
                                                 float* __restrict__ idxf_out,
                                                 float* __restrict__ qout) {
    __shared__ short8v s_bh[4096];     // 64 KB
    __shared__ short8v s_bl[4096];     // 64 KB
    __shared__ float   s_nb[NUM_CODES];          // 4 KB
    __shared__ unsigned s_win[4][ROWS_PER_ABLOCK]; // 8 KB
    __shared__ int     s_kwin[ROWS_PER_ABLOCK];    // 2 KB

    const int tid  = threadIdx.x;
    const int lane = tid & 63;
    const int wave = tid >> 6;        // 0..15
    const int c    = wave & 3;        // chunk
    const int wrg  = wave >> 2;       // rowgroup
    const int blockbase = blockIdx.x * ROWS_PER_ABLOCK;
    const int lr = lane & 15;   // A row / B,C col within frag
    const int lg = lane >> 4;   // k-group
    const int t0 = c * TILES_PER_CHUNK;

    // ---- stage B tables + nbias into LDS (whole block cooperates) ----
    {
        const short8v* gh = (const short8v*)bhi_g;
        const short8v* gl = (const short8v*)blo_g;
#pragma unroll
        for (int i = 0; i < 4; ++i) {
            s_bh[i * 1024 + tid] = gh[i * 1024 + tid];
            s_bl[i * 1024 + tid] = gl[i * 1024 + tid];
        }
        if (tid < NUM_CODES) s_nb[tid] = nbias[tid];
    }
    __syncthreads();   // B tables ready

#pragma unroll 1
    for (int pass = 0; pass < 2; ++pass) {
        const int rowbase = blockbase + pass * 256 + wrg * 64;

        // ---- load + hi/lo split A (4 row-frags = 64 rows per wave) ----
        short8v ahi[4], alo[4];
#pragma unroll
        for (int rf = 0; rf < 4; ++rf) {
            const float* src = flat + (size_t)(rowbase + rf * 16 + lr) * DIM + lg * 8;
            float4 f0 = *(const float4*)src;
            float4 f1 = *(const float4*)(src + 4);
            float fv[8] = {f0.x, f0.y, f0.z, f0.w, f1.x, f1.y, f1.z, f1.w};
            short8v h, lo;
#pragma unroll
            for (int j = 0; j < 8; ++j) {
                unsigned short hb = bf16_rne(fv[j]);
                float hf = __uint_as_float((unsigned)hb << 16);
                h[j]  = (short)hb;
                lo[j] = (short)bf16_rne(fv[j] - hf);
            }
            ahi[rf] = h; alo[rf] = lo;
        }

        unsigned best[4][4];
#pragma unroll
        for (int rf = 0; rf < 4; ++rf)
#pragma unroll
            for (int q = 0; q < 4; ++q) best[rf][q] = 0xFFFFFFFFu;

#pragma unroll 2
        for (int tt = 0; tt < TILES_PER_CHUNK; ++tt) {
            const int t = t0 + tt;
            short8v bh = s_bh[t * 64 + lane];
            short8v bl = s_bl[t * 64 + lane];
            float nn   = s_nb[t * 16 + lr];
            unsigned code = (unsigned)(t * 16 + lr);
#pragma unroll
            for (int rf = 0; rf < 4; ++rf) {
                f32x4 acc = {nn, nn, nn, nn};
                acc = __builtin_amdgcn_mfma_f32_16x16x32_bf16(ahi[rf], bh, acc, 0, 0, 0);
                acc = __builtin_amdgcn_mfma_f32_16x16x32_bf16(ahi[rf], bl, acc, 0, 0, 0);
                acc = __builtin_amdgcn_mfma_f32_16x16x32_bf16(alo[rf], bh, acc, 0, 0, 0);
#pragma unroll
                for (int q = 0; q < 4; ++q) {
                    unsigned pb = (__float_as_uint(acc[q]) & 0xFFFFFC00u) | code;
                    best[rf][q] = min(best[rf][q], pb);
                }
            }
        }

        // u32-min reduce across the 16-lane group; stash per-(chunk,row) winner
#pragma unroll
        for (int rf = 0; rf < 4; ++rf) {
#pragma unroll
            for (int q = 0; q < 4; ++q) {
                unsigned b = best[rf][q];
#pragma unroll
                for (int m = 1; m < 16; m <<= 1)
                    b = min(b, (unsigned)__shfl_xor((int)b, m));
                if (lr == q)
                    s_win[c][pass * 256 + wrg * 64 + rf * 16 + lg * 4 + q] = b;
            }
        }
    }
    __syncthreads();

    if (tid < ROWS_PER_ABLOCK) {
        unsigned pm = min(min(s_win[0][tid], s_win[1][tid]),
                          min(s_win[2][tid], s_win[3][tid]));
        int k = (int)(pm & 1023u);
        s_kwin[tid] = k;
        idx_out[blockbase + tid]  = k;
        idxf_out[blockbase + tid] = (float)k;
    }
    __syncthreads();

    // quantized write: 8 threads per row, coalesced, 4 passes over 512 rows
#pragma unroll
    for (int h = 0; h < 4; ++h) {
        int i2  = h * 1024 + tid;
        int row = i2 >> 3, seg = i2 & 7;
        int k = s_kwin[row];
        float4 e = *(const float4*)(emb + (size_t)k * DIM + seg * 4);
        *(float4*)(qout + (size_t)(blockbase + row) * DIM + seg * 4) = e;
    }
}

// ---------------- K2: stats — LDS-accumulated counts/dw + sum(f^2) ---------
// 256 blocks (1/CU, 132 KB LDS) x 512 threads (8 waves): one row per thread.
__global__ __launch_bounds__(512) void k_scatter(const float* __restrict__ flat,
                                                 const int* __restrict__ idx,
                                                 float* __restrict__ slabs,
                                                 float* __restrict__ sumf2,
                                                 int rows_per_block) {
    __shared__ float acc[SLAB];   // 132 KB
    __shared__ float red[512];
    const int tid = threadIdx.x;
    for (int i = tid; i < SLAB; i += 512) acc[i] = 0.0f;
    __syncthreads();

    const int row0 = blockIdx.x * rows_per_block;
    float sf = 0.0f;
    for (int rr = 0; rr < rows_per_block; rr += 512) {
        int r = row0 + rr + tid;
        int k = idx[r];
        const float4* f4 = (const float4*)(flat + (size_t)r * DIM);
        int kb = k * DIM;
#pragma unroll
        for (int j4 = 0; j4 < 8; ++j4) {
            float4 f = f4[j4];
            sf += f.x * f.x + f.y * f.y + f.z * f.z + f.w * f.w;
            int j = 4 * j4;
            // swizzled LDS layout: entry (k,j) lives at k*32 + ((j+k)&31)
            atomicAdd(&acc[kb + ((j + 0 + k) & 31)], f.x);
            atomicAdd(&acc[kb + ((j + 1 + k) & 31)], f.y);
            atomicAdd(&acc[kb + ((j + 2 + k) & 31)], f.z);
            atomicAdd(&acc[kb + ((j + 3 + k) & 31)], f.w);
        }
        atomicAdd(&acc[32768 + k], 1.0f);
    }
    __syncthreads();

    // flush LDS -> per-block slab (un-swizzle; coalesced global writes)
    float* slab = slabs + (size_t)blockIdx.x * SLAB;
    for (int i = tid; i < 32768; i += 512) {
        int k = i >> 5, j = i & 31;
        slab[i] = acc[(i & ~31) | ((j + k) & 31)];
    }
    for (int i = tid; i < NUM_CODES; i += 512) slab[32768 + i] = acc[32768 + i];

    red[tid] = sf;
    __syncthreads();
    for (int s = 256; s > 0; s >>= 1) {
        if (tid < s) red[tid] += red[tid + s];
        __syncthreads();
    }
    if (tid == 0) atomicAdd(sumf2, red[0]);
}

// ---------------- K2b: single-stage parallel slab reduction ----------------
// 132 blocks x 256 threads; each thread sums P strided values (coalesced
// within a block; BW-bound, plenty of wave TLP across 132 blocks).
__global__ __launch_bounds__(256) void k_reduce(const float* __restrict__ slabs,
                                                float* __restrict__ dw_sum,
                                                float* __restrict__ counts_sum,
                                                int P) {
    int i = blockIdx.x * 256 + threadIdx.x;
    float s = 0.0f;
#pragma unroll 4
    for (int p = 0; p < P; ++p) s += slabs[(size_t)p * SLAB + i];
    if (i < 32768) dw_sum[i] = s;
    else           counts_sum[i - 32768] = s;
}

// ---------------- K3: finalize (single block, 1024 threads; reads 132 KB) ----
// loss via identity:
// sum||e-f||^2 = sum||f||^2 + sum_k c_k||e_k||^2 - 2 sum e_k . dw_k  (f64 accum)
__global__ __launch_bounds__(1024) void k_final(const float* __restrict__ ema_cs,
                                                const float* __restrict__ ema_w,
                                                const float* __restrict__ emb,
                                                const float* __restrict__ counts,
                                                const float* __restrict__ dw,
                                                const float* __restrict__ sumf2,
                                                float* __restrict__ out_loss,
                                                float* __restrict__ out_perp,
                                                float* __restrict__ out_emb,
                                                float* __restrict__ out_cs,
                                                float* __restrict__ out_ema_w) {
    int tid = threadIdx.x;
    __shared__ float s_cs[NUM_CODES];
    __shared__ float s_cnt[NUM_CODES];
    __shared__ float red[1024];
    __shared__ double redd[1024];

    float c = counts[tid];
    s_cnt[tid] = c;
    float pre = ema_cs[tid] * DECAYF + (1.0f - DECAYF) * c;

    red[tid] = pre;
    __syncthreads();
    for (int s = 512; s > 0; s >>= 1) {
        if (tid < s) red[tid] += red[tid + s];
        __syncthreads();
    }
    float n = red[0];
    __syncthreads();

    float ncs = (pre + EPSF) / (n + (float)NUM_CODES * EPSF) * n;
    s_cs[tid] = ncs;
    out_cs[tid] = ncs;

    float p = c / (float)ROWS;
    red[tid] = p * logf(p + 1e-10f);
    __syncthreads();
    for (int s = 512; s > 0; s >>= 1) {
        if (tid < s) red[tid] += red[tid + s];
        __syncthreads();
    }
    float nplogp = red[0];
    __syncthreads();

    // dw pass: EMA update, new embedding, and loss terms
    double lterm = 0.0;   // c_k e^2 - 2 e . dw, accumulated elementwise
    for (int i = tid; i < NUM_CODES * DIM; i += 1024) {
        int k = i >> 5;
        float dwv = dw[i];
        float e = emb[i];
        lterm += (double)e * ((double)e * (double)s_cnt[k] - 2.0 * (double)dwv);
        float w = ema_w[i] * DECAYF + (1.0f - DECAYF) * dwv;
        out_ema_w[i] = w;
        out_emb[i] = w / s_cs[k];
    }
    redd[tid] = lterm;
    __syncthreads();
    for (int s = 512; s > 0; s >>= 1) {
        if (tid < s) redd[tid] += redd[tid + s];
        __syncthreads();
    }
    if (tid == 0) {
        double lsum = (double)sumf2[0] + redd[0];
        out_loss[0] = (float)(CCOST * lsum / (double)((size_t)ROWS * DIM));
        out_perp[0] = expf(-nplogp);
    }
}

extern "C" void kernel_launch(void* const* d_in, const int* in_sizes, int n_in,
                              void* d_out, int out_size, void* d_ws, size_t ws_size,
                              hipStream_t stream) {
    const float* inputs    = (const float*)d_in[0];   // [16384,256]
    const float* embedding = (const float*)d_in[1];   // [1024,32]
    const float* ema_cs    = (const float*)d_in[2];   // [1024]
    const float* ema_w     = (const float*)d_in[3];   // [1024,32]

    // output layout (flat f32, return order)
    float* out        = (float*)d_out;
    float* out_loss   = out;                       // 1
    float* out_q      = out + 1;                   // 4194304
    float* out_perp   = out + 4194305;             // 1
    float* out_idxf   = out + 4194306;             // 131072
    float* out_emb    = out + 4325378;             // 32768
    float* out_cs     = out + 4358146;             // 1024
    float* out_ema_w  = out + 4359170;             // 32768

    // workspace layout (bytes)
    char* ws = (char*)d_ws;
    float* nbias      = (float*)(ws);                // 1024 f32   @ 0
    float* sumf2      = (float*)(ws + 4096);         // 1 f32      @ 4096
    int*   idx        = (int*)(ws + 8192);           // 131072 i32 @ 8192 .. 532480
    unsigned short* bhi_g = (unsigned short*)(ws + 532480);  // 64 KB .. 598016
    unsigned short* blo_g = (unsigned short*)(ws + 598016);  // 64 KB .. 663552
    float* dw_sum     = (float*)(ws + 663552);       // 32768 f32 .. 794624
    float* counts_sum = (float*)(ws + 794624);       // 1024 f32  .. 798720
    float* slabs      = (float*)(ws + 798720);       // P * 33792 f32

    size_t slab_off = 798720;
    size_t avail = (ws_size > slab_off) ? (ws_size - slab_off) : 0;
    int P = 64;   // fallback
    if (avail >= (size_t)256 * SLAB * 4) P = 256;
    else if (avail >= (size_t)128 * SLAB * 4) P = 128;
    int rows_per_block = ROWS / P;

    k_prep   <<<16, 256, 0, stream>>>(embedding, bhi_g, blo_g, nbias, sumf2);
    k_argmin <<<ROWS / ROWS_PER_ABLOCK, 1024, 0, stream>>>(inputs, bhi_g, blo_g,
                                                           nbias, embedding,
                                                           idx, out_idxf, out_q);
    k_scatter<<<P, 512, 0, stream>>>(inputs, idx, slabs, sumf2, rows_per_block);
    k_reduce <<<IBLK, 256, 0, stream>>>(slabs, dw_sum, counts_sum, P);
    k_final  <<<1, 1024, 0, stream>>>(ema_cs, ema_w, embedding, counts_sum, dw_sum,
                                      sumf2, out_loss, out_perp, out_emb, out_cs,
                                      out_ema_w);
}